// Round 10
// baseline (708.436 us; speedup 1.0000x reference)
//
#include <hip/hip_runtime.h>
#include <hip/hip_bf16.h>

typedef __bf16 bf16x8_t __attribute__((ext_vector_type(8)));
typedef __bf16 bf16x4_t __attribute__((ext_vector_type(4)));
typedef short s16x4_t  __attribute__((ext_vector_type(4)));
typedef float f32x4_t  __attribute__((ext_vector_type(4)));

#define NB 2
#define NS 2048
#define NHID 3584
#define NHEADS 16
#define NKVH 8
#define DH 256
#define WIN 1024

__device__ __forceinline__ float bf2f(ushort u) {
  union { unsigned v; float f; } x; x.v = ((unsigned)u) << 16; return x.f;
}
__device__ __forceinline__ ushort f2bf(float f) {
  unsigned x = __builtin_bit_cast(unsigned, f);
  unsigned r = (x + 0x7fffu + ((x >> 16) & 1u)) >> 16;
  return (ushort)r;
}

__device__ __forceinline__ void gload16(const void* g, void* l) {
  __builtin_amdgcn_global_load_lds((const __attribute__((address_space(1))) void*)g,
                                   (__attribute__((address_space(3))) void*)l, 16, 0, 0);
}

__device__ __forceinline__ f32x4_t mfma_pv(s16x4_t a, s16x4_t b, f32x4_t c) {
#if __has_builtin(__builtin_amdgcn_mfma_f32_16x16x16_bf16)
  return __builtin_amdgcn_mfma_f32_16x16x16_bf16(
      __builtin_bit_cast(bf16x4_t, a), __builtin_bit_cast(bf16x4_t, b), c, 0, 0, 0);
#else
  return __builtin_amdgcn_mfma_f32_16x16x16bf16_1k(a, b, c, 0, 0, 0);
#endif
}

// p = exp(50*tanh((s/16)/50)); x = s/800; bounded by e^50 (fixed-max softmax safe)
__device__ __forceinline__ float pexp(float s) {
  float e = __expf(fminf(s * 0.0025f, 80.f));
  float th = __fdividef(e - 1.f, e + 1.f);
  return __expf(50.f * th);
}

// ---------------- f32 -> bf16 elementwise convert (x4 vectorized) ---------
__global__ __launch_bounds__(256) void f32_to_bf16_kernel(const float* __restrict__ in,
                                                          ushort* __restrict__ out, int n4) {
  int i = (int)blockIdx.x * 256 + (int)threadIdx.x;
  if (i < n4) {
    float4 v = ((const float4*)in)[i];
    ushort4 o;
    o.x = f2bf(v.x); o.y = f2bf(v.y); o.z = f2bf(v.z); o.w = f2bf(v.w);
    ((ushort4*)out)[i] = o;
  }
}

// ------------- transpose+convert: f32 in[R][C] -> bf16 out[C][R] ----------
__global__ __launch_bounds__(256) void transpose_f32_bf16(const float* __restrict__ in,
                                                          ushort* __restrict__ out,
                                                          int R, int Cc) {
  __shared__ ushort tile[64][72];
  const int t = threadIdx.x;
  const int ct = Cc >> 6;
  const int by = blockIdx.x / ct;
  const int bx = blockIdx.x % ct;
  const int r0 = by << 6, c0 = bx << 6;
#pragma unroll
  for (int i = 0; i < 16; ++i) {
    int idx = i * 256 + t;
    int r = idx >> 6, c = idx & 63;
    tile[r][c] = f2bf(in[(size_t)(r0 + r) * Cc + c0 + c]);
  }
  __syncthreads();
#pragma unroll
  for (int i = 0; i < 16; ++i) {
    int idx = i * 256 + t;
    int rr = idx >> 6, cc = idx & 63;
    out[(size_t)(c0 + rr) * R + r0 + cc] = tile[cc][rr];
  }
}

// ============ 8-phase 256x256 GEMM: C = A[M][K] * Bt[N][K]^T ==============
#define GSYNC1 do { __builtin_amdgcn_s_barrier(); \
    asm volatile("s_waitcnt lgkmcnt(0)" ::: "memory"); \
    __builtin_amdgcn_sched_barrier(0); } while (0)
#define GSYNC2(st) do { \
    if (st) asm volatile("s_waitcnt vmcnt(2)" ::: "memory"); \
    else    asm volatile("s_waitcnt vmcnt(0)" ::: "memory"); \
    __builtin_amdgcn_sched_barrier(0); \
    __builtin_amdgcn_s_barrier(); } while (0)

template <int EPI>
__global__ __launch_bounds__(512, 2) void gemm256(const ushort* __restrict__ A,
                                                  const ushort* __restrict__ Bt,
                                                  void* __restrict__ Cout,
                                                  int M, int N, int K) {
  __shared__ alignas(16) char lds[131072];
  const int t = threadIdx.x;
  const int lane = t & 63;
  const int wid = t >> 6;
  const int wm = wid >> 2;   // 0..1
  const int wn = wid & 3;    // 0..3
  const int g = lane >> 4;
  const int lr = lane & 15;
  const int lrow8 = lane >> 3;
  const int lp = (lane & 7) ^ lrow8;  // pre-swizzled staging chunk

  const int nbn = N >> 8;
  const int nwg = (int)gridDim.x;
  const int bid = (int)blockIdx.x;
  const int swz = (bid & 7) * (nwg >> 3) + (bid >> 3);
  const int bm = swz / nbn, bn = swz % nbn;
  const int m0 = bm << 8, n0 = bn << 8;

  f32x4_t acc[8][4] = {};
  const int T = K >> 6;

  auto stageA = [&](int q, int koff, int bufn) {
    int row = (q << 6) + (wid << 3) + lrow8;
    gload16(A + (size_t)(m0 + row) * K + koff + (lp << 3),
            lds + bufn * 32768 + (q << 13) + (wid << 10));
  };
  auto stageB = [&](int q, int koff, int bufn) {
    int row = (q << 6) + (wid << 3) + lrow8;
    gload16(Bt + (size_t)(n0 + row) * K + koff + (lp << 3),
            lds + 65536 + bufn * 32768 + (q << 13) + (wid << 10));
  };

  // prologue: tile 0 -> buf 0
#pragma unroll
  for (int q = 0; q < 4; ++q) { stageA(q, 0, 0); stageB(q, 0, 0); }
  asm volatile("s_waitcnt vmcnt(0)" ::: "memory");
  __builtin_amdgcn_s_barrier();

  for (int tt = 0; tt < T; ++tt) {
    const int bc = tt & 1;
    const int bnx = bc ^ 1;
    const bool st = (tt + 1 < T);
    const int kn = (tt + 1) << 6;
    const char* cA = lds + bc * 32768;
    const char* cB = lds + 65536 + bc * 32768;
    bf16x8_t af[4], bfv[4];

    auto ldA = [&](int i, int mh, int ks) {
      int row = (wm << 7) + (mh << 6) + (i << 4) + lr;
      af[i] = *(const bf16x8_t*)(cA + (row << 7) + (((ks << 6) + (g << 4)) ^ ((row & 7) << 4)));
    };
    auto ldB = [&](int j, int ks) {
      int row = (wn << 6) + (j << 4) + lr;
      bfv[j] = *(const bf16x8_t*)(cB + (row << 7) + (((ks << 6) + (g << 4)) ^ ((row & 7) << 4)));
    };

    // ---- phase 0: mh0, ks0 ----
#pragma unroll
    for (int i = 0; i < 4; ++i) ldA(i, 0, 0);
#pragma unroll
    for (int j = 0; j < 4; ++j) ldB(j, 0);
    if (st) { stageA(0, kn, bnx); stageA(2, kn, bnx); }
    GSYNC1;
    __builtin_amdgcn_s_setprio(1);
#pragma unroll
    for (int i = 0; i < 4; ++i)
#pragma unroll
      for (int j = 0; j < 4; ++j)
        acc[i][j] = __builtin_amdgcn_mfma_f32_16x16x32_bf16(af[i], bfv[j], acc[i][j], 0, 0, 0);
    __builtin_amdgcn_s_setprio(0);
    GSYNC2(st);

    // ---- phase 1: mh1, ks0 ----
#pragma unroll
    for (int i = 0; i < 4; ++i) ldA(i, 1, 0);
    if (st) { stageB(0, kn, bnx); stageB(1, kn, bnx); }
    GSYNC1;
    __builtin_amdgcn_s_setprio(1);
#pragma unroll
    for (int i = 0; i < 4; ++i)
#pragma unroll
      for (int j = 0; j < 4; ++j)
        acc[4 + i][j] = __builtin_amdgcn_mfma_f32_16x16x32_bf16(af[i], bfv[j], acc[4 + i][j], 0, 0, 0);
    __builtin_amdgcn_s_setprio(0);
    GSYNC2(st);

    // ---- phase 2: mh0, ks1 ----
#pragma unroll
    for (int i = 0; i < 4; ++i) ldA(i, 0, 1);
#pragma unroll
    for (int j = 0; j < 4; ++j) ldB(j, 1);
    if (st) { stageB(2, kn, bnx); stageB(3, kn, bnx); }
    GSYNC1;
    __builtin_amdgcn_s_setprio(1);
#pragma unroll
    for (int i = 0; i < 4; ++i)
#pragma unroll
      for (int j = 0; j < 4; ++j)
        acc[i][j] = __builtin_amdgcn_mfma_f32_16x16x32_bf16(af[i], bfv[j], acc[i][j], 0, 0, 0);
    __builtin_amdgcn_s_setprio(0);
    GSYNC2(st);

    // ---- phase 3: mh1, ks1 ----
#pragma unroll
    for (int i = 0; i < 4; ++i) ldA(i, 1, 1);
    if (st) { stageA(1, kn, bnx); stageA(3, kn, bnx); }
    GSYNC1;
    __builtin_amdgcn_s_setprio(1);
#pragma unroll
    for (int i = 0; i < 4; ++i)
#pragma unroll
      for (int j = 0; j < 4; ++j)
        acc[4 + i][j] = __builtin_amdgcn_mfma_f32_16x16x32_bf16(af[i], bfv[j], acc[4 + i][j], 0, 0, 0);
    __builtin_amdgcn_s_setprio(0);
    GSYNC2(st);
  }

  // ---- epilogue ----
  __syncthreads();
  const bool trstage = (EPI == 4) && (n0 >= 2048);
  if (trstage) {
#pragma unroll
    for (int i = 0; i < 8; ++i)
#pragma unroll
      for (int j = 0; j < 4; ++j) {
        int col = (wn << 6) + (j << 4) + lr;
#pragma unroll
        for (int r = 0; r < 4; ++r) {
          int row = (wm << 7) + (i << 4) + (g << 2) + r;
          *(ushort*)(lds + (col << 9) + ((row << 1) ^ ((col & 7) << 4))) = f2bf(acc[i][j][r]);
        }
      }
  } else {
#pragma unroll
    for (int i = 0; i < 8; ++i)
#pragma unroll
      for (int j = 0; j < 4; ++j) {
        int col = (wn << 6) + (j << 4) + lr;
#pragma unroll
        for (int r = 0; r < 4; ++r) {
          int row = (wm << 7) + (i << 4) + (g << 2) + r;
          *(ushort*)(lds + (row << 9) + ((col << 1) ^ ((row & 7) << 4))) = f2bf(acc[i][j][r]);
        }
      }
  }
  __syncthreads();

  if (EPI == 0) {
    ushort* C = (ushort*)Cout;
#pragma unroll
    for (int it = 0; it < 16; ++it) {
      int idx = it * 512 + t;
      int row = idx >> 5, ch = idx & 31;
      uint4 v = *(const uint4*)(lds + (row << 9) + ((ch << 4) ^ ((row & 7) << 4)));
      *(uint4*)(C + (size_t)(m0 + row) * N + n0 + (ch << 3)) = v;
    }
  } else if (EPI == 4) {
    ushort* C = (ushort*)Cout;
    if (n0 < 2048) {
#pragma unroll
      for (int it = 0; it < 16; ++it) {
        int idx = it * 512 + t;
        int row = idx >> 5, ch = idx & 31;
        uint4 v = *(const uint4*)(lds + (row << 9) + ((ch << 4) ^ ((row & 7) << 4)));
        *(uint4*)(C + (size_t)(m0 + row) * 2048 + n0 + (ch << 3)) = v;
      }
    } else {
      ushort* vC = C + (size_t)4096 * 2048;
      const int bb = m0 >> 11;
      const int ss = m0 & (NS - 1);
#pragma unroll
      for (int it = 0; it < 16; ++it) {
        int idx = it * 512 + t;
        int dc = idx >> 5, ch = idx & 31;
        uint4 v = *(const uint4*)(lds + (dc << 9) + ((ch << 4) ^ ((dc & 7) << 4)));
        int gc = (n0 - 2048) + dc;
        int kvh = gc >> 8, d = gc & 255;
        *(uint4*)(vC + ((size_t)((bb * NKVH + kvh) * DH + d)) * NS + ss + (ch << 3)) = v;
      }
    }
  } else {
    float* Cf = (float*)Cout;
#pragma unroll
    for (int it = 0; it < 32; ++it) {
      int idx = it * 512 + t;
      int row = idx >> 6, qd = idx & 63;
      ushort4 hv = *(const ushort4*)(lds + (row << 9) + ((qd << 3) ^ ((row & 7) << 4)));
      float4 fv;
      fv.x = bf2f(hv.x); fv.y = bf2f(hv.y); fv.z = bf2f(hv.z); fv.w = bf2f(hv.w);
      *(float4*)(Cf + (size_t)(m0 + row) * N + n0 + (qd << 2)) = fv;
    }
  }
}

// ---------------- RoPE in-place on bf16 [B*S][nheads*256], pairs (d,d+128) -
__global__ __launch_bounds__(256) void rope_kernel(ushort* __restrict__ buf,
                                                   const float* __restrict__ sint,
                                                   const float* __restrict__ cost,
                                                   int nheads) {
  int idx = (int)blockIdx.x * 256 + (int)threadIdx.x;
  int d = idx & 127;
  int h = (idx >> 7) % nheads;
  int tok = idx / (nheads << 7);
  int pos = tok & (NS - 1);
  float c = cost[pos * DH + d];
  float s = sint[pos * DH + d];
  size_t base = (size_t)tok * ((size_t)nheads * DH) + h * DH + d;
  float x1 = bf2f(buf[base]);
  float x2 = bf2f(buf[base + 128]);
  buf[base] = f2bf(x1 * c - x2 * s);
  buf[base + 128] = f2bf(x2 * c + x1 * s);
}

// ---------------- flash attention v3: single-buffer + T14 reg-staging ------
// grid: B*NH*(S/64) = 1024; block 256 = 4 waves, each wave 16 q-rows.
// LDS 32KB (K 16K + V 16K) -> 5 blocks/CU resident (was 2): latency hidden by TLP.
// Reg-staged K/V: load(t+2)->regs issued after ds_write(t+1); compiler inserts
// the vmcnt via the register dependence. 2 barriers/iter.
// V layout [dt=16][kq=8][lr=16]x8B: PV read granule == lr -> conflict-free
// (bijective per 16-lane phase); staging write granule == d&15 -> conflict-free.
// K layout [32 rows][512B], 16B-chunk XOR (row&7) (GEMM-proven, 0 conflicts).
__global__ __launch_bounds__(256) void attn_kernel(const ushort* __restrict__ q,
                                                   const ushort* __restrict__ k,
                                                   const ushort* __restrict__ vt,
                                                   ushort* __restrict__ ao) {
  __shared__ alignas(16) char lK[16384];
  __shared__ alignas(16) char lV[16384];
  const int bid = (int)blockIdx.x;
  const int qb = bid & 31;
  const int h = (bid >> 5) & 15;
  const int b = bid >> 9;
  const int kvh = h >> 1;
  const int qb0 = qb << 6;
  const int t = threadIdx.x;
  const int lane = t & 63;
  const int w = t >> 6;
  const int g = lane >> 4;
  const int lr = lane & 15;

  const int qrow = qb0 + (w << 4) + lr;
  bf16x8_t qf[8];
  const ushort* qbase = q + (size_t)(b * NS + qrow) * (NHEADS * DH) + h * DH;
#pragma unroll
  for (int ks = 0; ks < 8; ++ks)
    qf[ks] = *(const bf16x8_t*)(qbase + (ks << 5) + (g << 3));

  float l_r = 0.f;
  f32x4_t oacc[16] = {};

  const int qminw = qb0 + (w << 4);
  const int qmaxw = qminw + 15;
  int t_lo = qb0 - (WIN - 1);
  if (t_lo < 0) t_lo = 0;
  t_lo &= ~31;
  const int t_hi = qb0 + 63;
  const int nt = ((t_hi - t_lo) >> 5) + 1;

  const ushort* kgb = k + (size_t)(b * NS) * (NKVH * DH) + kvh * DH;
  const ushort* vgb = vt + (size_t)((b * NKVH + kvh) * DH) * NS;

  // staging maps: K: thread -> (row=t>>3, 64B at chunk16 base (t&7)*4)
  //               V: thread -> d=t, 64B (32 keys)
  const int krow = t >> 3;
  const int kc16 = (t & 7) << 2;
  uint4 kr[4], vr[4];

  auto ldreg = [&](int kt) {
    const ushort* ks = kgb + (size_t)(kt + krow) * (NKVH * DH) + (kc16 << 3);
#pragma unroll
    for (int j = 0; j < 4; ++j) kr[j] = *(const uint4*)(ks + (j << 3));
    const ushort* vs = vgb + (size_t)t * NS + kt;
#pragma unroll
    for (int j = 0; j < 4; ++j) vr[j] = *(const uint4*)(vs + (j << 3));
  };
  auto wlds = [&]() {
#pragma unroll
    for (int j = 0; j < 4; ++j) {
      int pc = (kc16 + j) ^ (krow & 7);
      *(uint4*)(lK + (krow << 9) + (pc << 4)) = kr[j];
    }
    char* vb = lV + ((t >> 4) << 10) + ((t & 15) << 3);
#pragma unroll
    for (int j = 0; j < 4; ++j) {
      uint2 lo; lo.x = vr[j].x; lo.y = vr[j].y;
      uint2 hi; hi.x = vr[j].z; hi.y = vr[j].w;
      *(uint2*)(vb + ((j << 1) << 7)) = lo;
      *(uint2*)(vb + (((j << 1) | 1) << 7)) = hi;
    }
  };

  // prologue
  ldreg(t_lo);
  wlds();  // compiler waits vmcnt before ds_write (reg dependence)
  if (nt > 1) ldreg(t_lo + 32);
  __syncthreads();

  for (int i = 0; i < nt; ++i) {
    const int kt = t_lo + (i << 5);
#pragma unroll
    for (int sub = 0; sub < 2; ++sub) {
      const int key0 = kt + (sub << 4);
      if (key0 > qmaxw) continue;
      if (key0 + 15 < qminw - (WIN - 1)) continue;

      f32x4_t sacc = {};
      __builtin_amdgcn_s_setprio(1);
#pragma unroll
      for (int ks = 0; ks < 8; ++ks) {
        int row = (sub << 4) + lr;
        bf16x8_t kf = *(const bf16x8_t*)(lK + (((row << 9) + (ks << 6) + (g << 4)) ^ ((row & 7) << 4)));
        sacc = __builtin_amdgcn_mfma_f32_16x16x32_bf16(kf, qf[ks], sacc, 0, 0, 0);
      }
      __builtin_amdgcn_s_setprio(0);

      float pvv[4];
      const bool full = (key0 + 15 <= qminw) && (key0 >= qmaxw - (WIN - 1));
      if (full) {
#pragma unroll
        for (int r = 0; r < 4; ++r) { pvv[r] = pexp(sacc[r]); l_r += pvv[r]; }
      } else {
#pragma unroll
        for (int r = 0; r < 4; ++r) {
          int key = key0 + (g << 2) + r;
          bool ok = (key <= qrow) && (qrow - key < WIN);
          pvv[r] = ok ? pexp(sacc[r]) : 0.f;
          l_r += pvv[r];
        }
      }

      s16x4_t pa;
      pa[0] = (short)f2bf(pvv[0]);
      pa[1] = (short)f2bf(pvv[1]);
      pa[2] = (short)f2bf(pvv[2]);
      pa[3] = (short)f2bf(pvv[3]);

      const int vsub = ((sub << 2) + g) << 7;  // kq stripe
      __builtin_amdgcn_s_setprio(1);
#pragma unroll
      for (int dt = 0; dt < 16; ++dt) {
        s16x4_t vf = *(const s16x4_t*)(lV + (dt << 10) + vsub + (lr << 3));
        oacc[dt] = mfma_pv(pa, vf, oacc[dt]);
      }
      __builtin_amdgcn_s_setprio(0);
    }
    __syncthreads();  // all waves done reading tile i
    if (i + 1 < nt) {
      wlds();  // tile i+1 regs -> LDS (vmcnt auto)
      if (i + 2 < nt) ldreg(t_lo + ((i + 2) << 5));
      __syncthreads();  // writes visible before compute(i+1)
    }
  }

  l_r += __shfl_xor(l_r, 16);
  l_r += __shfl_xor(l_r, 32);
  float dn[4];
#pragma unroll
  for (int r = 0; r < 4; ++r)
    dn[r] = 1.0f / __shfl(l_r, (g << 2) + r);

  const int orow0 = b * NS + qb0 + (w << 4) + (g << 2);
#pragma unroll
  for (int dt = 0; dt < 16; ++dt) {
    int col = h * DH + (dt << 4) + lr;
#pragma unroll
    for (int r = 0; r < 4; ++r) {
      ao[(size_t)(orow0 + r) * (NHEADS * DH) + col] = f2bf(oacc[dt][r] * dn[r]);
    }
  }
}

extern "C" void kernel_launch(void* const* d_in, const int* in_sizes, int n_in,
                              void* d_out, int out_size, void* d_ws, size_t ws_size,
                              hipStream_t stream) {
  const float* hs   = (const float*)d_in[0];
  const float* sint = (const float*)d_in[3];
  const float* cost = (const float*)d_in[4];
  const float* Wq = (const float*)d_in[6];
  const float* Wk = (const float*)d_in[7];
  const float* Wv = (const float*)d_in[8];
  const float* Wo = (const float*)d_in[9];

  char* ws = (char*)d_ws;
  size_t off = 0;
  auto alloc = [&](size_t bytes) {
    char* p = ws + off;
    off += (bytes + 255) & ~(size_t)255;
    return p;
  };
  ushort* hsb   = (ushort*)alloc((size_t)4096 * 3584 * 2);  // hs in bf16
  ushort* wT    = (ushort*)alloc((size_t)4096 * 3584 * 2);  // reused weight^T buffer
  ushort* qbuf  = (ushort*)alloc((size_t)4096 * 4096 * 2);
  ushort* kbuf  = (ushort*)alloc((size_t)4096 * 2048 * 2);  // MUST precede vtbuf
  ushort* vtbuf = (ushort*)alloc((size_t)4096 * 2048 * 2);  // = kbuf + 4096*2048
  ushort* aobuf = qbuf;  // alias: attn writes exactly the region only it reads
  if (off > ws_size) return;

  // hs f32 -> bf16
  f32_to_bf16_kernel<<<(4096 * 3584 / 4) / 256, 256, 0, stream>>>(hs, hsb, 4096 * 3584 / 4);

  // fused K+V projection: Bt = [WkT; WvT] stacked in wT
  transpose_f32_bf16<<<(3584 / 64) * (2048 / 64), 256, 0, stream>>>(Wk, wT, 3584, 2048);
  transpose_f32_bf16<<<(3584 / 64) * (2048 / 64), 256, 0, stream>>>(Wv, wT + (size_t)2048 * 3584, 3584, 2048);
  gemm256<4><<<16 * 16, 512, 0, stream>>>(hsb, wT, kbuf, 4096, 4096, 3584);

  // Q projection
  transpose_f32_bf16<<<(3584 / 64) * (4096 / 64), 256, 0, stream>>>(Wq, wT, 3584, 4096);
  gemm256<0><<<16 * 16, 512, 0, stream>>>(hsb, wT, qbuf, 4096, 4096, 3584);

  // RoPE (q then k), in-place
  rope_kernel<<<(4096 * 16 * 128) / 256, 256, 0, stream>>>(qbuf, sint, cost, 16);
  rope_kernel<<<(4096 * 8 * 128) / 256, 256, 0, stream>>>(kbuf, sint, cost, 8);

  // attention: 1 head/block (ao aliases qbuf)
  attn_kernel<<<NB * NHEADS * (NS / 64), 256, 0, stream>>>(qbuf, kbuf, vtbuf, aobuf);

  // output projection, f32 out
  transpose_f32_bf16<<<(4096 / 64) * (3584 / 64), 256, 0, stream>>>(Wo, wT, 4096, 3584);
  gemm256<2><<<16 * 14, 512, 0, stream>>>(aobuf, wT, d_out, 4096, 3584, 4096);
}

// Round 12
// 603.099 us; speedup vs baseline: 1.1747x; 1.1747x over previous
//
#include <hip/hip_runtime.h>
#include <hip/hip_bf16.h>

typedef __bf16 bf16x8_t __attribute__((ext_vector_type(8)));
typedef __bf16 bf16x4_t __attribute__((ext_vector_type(4)));
typedef short s16x4_t  __attribute__((ext_vector_type(4)));
typedef float f32x4_t  __attribute__((ext_vector_type(4)));

#define NB 2
#define NS 2048
#define NHID 3584
#define NHEADS 16
#define NKVH 8
#define DH 256
#define WIN 1024

__device__ __forceinline__ float bf2f(ushort u) {
  union { unsigned v; float f; } x; x.v = ((unsigned)u) << 16; return x.f;
}
__device__ __forceinline__ ushort f2bf(float f) {
  unsigned x = __builtin_bit_cast(unsigned, f);
  unsigned r = (x + 0x7fffu + ((x >> 16) & 1u)) >> 16;
  return (ushort)r;
}

__device__ __forceinline__ void gload16(const void* g, void* l) {
  __builtin_amdgcn_global_load_lds((const __attribute__((address_space(1))) void*)g,
                                   (__attribute__((address_space(3))) void*)l, 16, 0, 0);
}

__device__ __forceinline__ f32x4_t mfma_pv(s16x4_t a, s16x4_t b, f32x4_t c) {
#if __has_builtin(__builtin_amdgcn_mfma_f32_16x16x16_bf16)
  return __builtin_amdgcn_mfma_f32_16x16x16_bf16(
      __builtin_bit_cast(bf16x4_t, a), __builtin_bit_cast(bf16x4_t, b), c, 0, 0, 0);
#else
  return __builtin_amdgcn_mfma_f32_16x16x16bf16_1k(a, b, c, 0, 0, 0);
#endif
}

// p = exp(50*tanh((s/16)/50)); x = s/800; bounded by e^50 (fixed-max softmax safe)
__device__ __forceinline__ float pexp(float s) {
  float e = __expf(fminf(s * 0.0025f, 80.f));
  float th = __fdividef(e - 1.f, e + 1.f);
  return __expf(50.f * th);
}

// ---------------- f32 -> bf16 elementwise convert (x4 vectorized) ---------
__global__ __launch_bounds__(256) void f32_to_bf16_kernel(const float* __restrict__ in,
                                                          ushort* __restrict__ out, int n4) {
  int i = (int)blockIdx.x * 256 + (int)threadIdx.x;
  if (i < n4) {
    float4 v = ((const float4*)in)[i];
    ushort4 o;
    o.x = f2bf(v.x); o.y = f2bf(v.y); o.z = f2bf(v.z); o.w = f2bf(v.w);
    ((ushort4*)out)[i] = o;
  }
}

// ------------- transpose+convert: f32 in[R][C] -> bf16 out[C][R] ----------
__global__ __launch_bounds__(256) void transpose_f32_bf16(const float* __restrict__ in,
                                                          ushort* __restrict__ out,
                                                          int R, int Cc) {
  __shared__ ushort tile[64][72];
  const int t = threadIdx.x;
  const int ct = Cc >> 6;
  const int by = blockIdx.x / ct;
  const int bx = blockIdx.x % ct;
  const int r0 = by << 6, c0 = bx << 6;
#pragma unroll
  for (int i = 0; i < 16; ++i) {
    int idx = i * 256 + t;
    int r = idx >> 6, c = idx & 63;
    tile[r][c] = f2bf(in[(size_t)(r0 + r) * Cc + c0 + c]);
  }
  __syncthreads();
#pragma unroll
  for (int i = 0; i < 16; ++i) {
    int idx = i * 256 + t;
    int rr = idx >> 6, cc = idx & 63;
    out[(size_t)(c0 + rr) * R + r0 + cc] = tile[cc][rr];
  }
}

// ============ 8-phase 256x256 GEMM: C = A[M][K] * Bt[N][K]^T ==============
#define GSYNC1 do { __builtin_amdgcn_s_barrier(); \
    asm volatile("s_waitcnt lgkmcnt(0)" ::: "memory"); \
    __builtin_amdgcn_sched_barrier(0); } while (0)
#define GSYNC2(st) do { \
    if (st) asm volatile("s_waitcnt vmcnt(2)" ::: "memory"); \
    else    asm volatile("s_waitcnt vmcnt(0)" ::: "memory"); \
    __builtin_amdgcn_sched_barrier(0); \
    __builtin_amdgcn_s_barrier(); } while (0)

// EPI=0: bf16 C[M][N]. EPI=2: f32 C. EPI=4: fused KV — K half -> kbuf rows;
// V half -> vtbuf in ATTN-TILED layout: elem(b,kvh, s, d) =
//   plane(b*8+kvh)*524288 + (s>>5)*8192 + (d>>4)*512 + ((s&31)>>2)*64 + (d&15)*4 + (s&3)
template <int EPI>
__global__ __launch_bounds__(512, 2) void gemm256(const ushort* __restrict__ A,
                                                  const ushort* __restrict__ Bt,
                                                  void* __restrict__ Cout,
                                                  int M, int N, int K) {
  __shared__ alignas(16) char lds[131072];
  const int t = threadIdx.x;
  const int lane = t & 63;
  const int wid = t >> 6;
  const int wm = wid >> 2;   // 0..1
  const int wn = wid & 3;    // 0..3
  const int g = lane >> 4;
  const int lr = lane & 15;
  const int lrow8 = lane >> 3;
  const int lp = (lane & 7) ^ lrow8;  // pre-swizzled staging chunk

  const int nbn = N >> 8;
  const int nwg = (int)gridDim.x;
  const int bid = (int)blockIdx.x;
  const int swz = (bid & 7) * (nwg >> 3) + (bid >> 3);
  const int bm = swz / nbn, bn = swz % nbn;
  const int m0 = bm << 8, n0 = bn << 8;

  f32x4_t acc[8][4] = {};
  const int T = K >> 6;

  auto stageA = [&](int q, int koff, int bufn) {
    int row = (q << 6) + (wid << 3) + lrow8;
    gload16(A + (size_t)(m0 + row) * K + koff + (lp << 3),
            lds + bufn * 32768 + (q << 13) + (wid << 10));
  };
  auto stageB = [&](int q, int koff, int bufn) {
    int row = (q << 6) + (wid << 3) + lrow8;
    gload16(Bt + (size_t)(n0 + row) * K + koff + (lp << 3),
            lds + 65536 + bufn * 32768 + (q << 13) + (wid << 10));
  };

  // prologue: tile 0 -> buf 0
#pragma unroll
  for (int q = 0; q < 4; ++q) { stageA(q, 0, 0); stageB(q, 0, 0); }
  asm volatile("s_waitcnt vmcnt(0)" ::: "memory");
  __builtin_amdgcn_s_barrier();

  for (int tt = 0; tt < T; ++tt) {
    const int bc = tt & 1;
    const int bnx = bc ^ 1;
    const bool st = (tt + 1 < T);
    const int kn = (tt + 1) << 6;
    const char* cA = lds + bc * 32768;
    const char* cB = lds + 65536 + bc * 32768;
    bf16x8_t af[4], bfv[4];

    auto ldA = [&](int i, int mh, int ks) {
      int row = (wm << 7) + (mh << 6) + (i << 4) + lr;
      af[i] = *(const bf16x8_t*)(cA + (row << 7) + (((ks << 6) + (g << 4)) ^ ((row & 7) << 4)));
    };
    auto ldB = [&](int j, int ks) {
      int row = (wn << 6) + (j << 4) + lr;
      bfv[j] = *(const bf16x8_t*)(cB + (row << 7) + (((ks << 6) + (g << 4)) ^ ((row & 7) << 4)));
    };

    // ---- phase 0: mh0, ks0 ----
#pragma unroll
    for (int i = 0; i < 4; ++i) ldA(i, 0, 0);
#pragma unroll
    for (int j = 0; j < 4; ++j) ldB(j, 0);
    if (st) { stageA(0, kn, bnx); stageA(2, kn, bnx); }
    GSYNC1;
    __builtin_amdgcn_s_setprio(1);
#pragma unroll
    for (int i = 0; i < 4; ++i)
#pragma unroll
      for (int j = 0; j < 4; ++j)
        acc[i][j] = __builtin_amdgcn_mfma_f32_16x16x32_bf16(af[i], bfv[j], acc[i][j], 0, 0, 0);
    __builtin_amdgcn_s_setprio(0);
    GSYNC2(st);

    // ---- phase 1: mh1, ks0 ----
#pragma unroll
    for (int i = 0; i < 4; ++i) ldA(i, 1, 0);
    if (st) { stageB(0, kn, bnx); stageB(1, kn, bnx); }
    GSYNC1;
    __builtin_amdgcn_s_setprio(1);
#pragma unroll
    for (int i = 0; i < 4; ++i)
#pragma unroll
      for (int j = 0; j < 4; ++j)
        acc[4 + i][j] = __builtin_amdgcn_mfma_f32_16x16x32_bf16(af[i], bfv[j], acc[4 + i][j], 0, 0, 0);
    __builtin_amdgcn_s_setprio(0);
    GSYNC2(st);

    // ---- phase 2: mh0, ks1 ----
#pragma unroll
    for (int i = 0; i < 4; ++i) ldA(i, 0, 1);
#pragma unroll
    for (int j = 0; j < 4; ++j) ldB(j, 1);
    if (st) { stageB(2, kn, bnx); stageB(3, kn, bnx); }
    GSYNC1;
    __builtin_amdgcn_s_setprio(1);
#pragma unroll
    for (int i = 0; i < 4; ++i)
#pragma unroll
      for (int j = 0; j < 4; ++j)
        acc[i][j] = __builtin_amdgcn_mfma_f32_16x16x32_bf16(af[i], bfv[j], acc[i][j], 0, 0, 0);
    __builtin_amdgcn_s_setprio(0);
    GSYNC2(st);

    // ---- phase 3: mh1, ks1 ----
#pragma unroll
    for (int i = 0; i < 4; ++i) ldA(i, 1, 1);
    if (st) { stageA(1, kn, bnx); stageA(3, kn, bnx); }
    GSYNC1;
    __builtin_amdgcn_s_setprio(1);
#pragma unroll
    for (int i = 0; i < 4; ++i)
#pragma unroll
      for (int j = 0; j < 4; ++j)
        acc[4 + i][j] = __builtin_amdgcn_mfma_f32_16x16x32_bf16(af[i], bfv[j], acc[4 + i][j], 0, 0, 0);
    __builtin_amdgcn_s_setprio(0);
    GSYNC2(st);
  }

  // ---- epilogue ----
  __syncthreads();
  const bool trstage = (EPI == 4) && (n0 >= 2048);
  if (trstage) {
#pragma unroll
    for (int i = 0; i < 8; ++i)
#pragma unroll
      for (int j = 0; j < 4; ++j) {
        int col = (wn << 6) + (j << 4) + lr;
#pragma unroll
        for (int r = 0; r < 4; ++r) {
          int row = (wm << 7) + (i << 4) + (g << 2) + r;
          *(ushort*)(lds + (col << 9) + ((row << 1) ^ ((col & 7) << 4))) = f2bf(acc[i][j][r]);
        }
      }
  } else {
#pragma unroll
    for (int i = 0; i < 8; ++i)
#pragma unroll
      for (int j = 0; j < 4; ++j) {
        int col = (wn << 6) + (j << 4) + lr;
#pragma unroll
        for (int r = 0; r < 4; ++r) {
          int row = (wm << 7) + (i << 4) + (g << 2) + r;
          *(ushort*)(lds + (row << 9) + ((col << 1) ^ ((row & 7) << 4))) = f2bf(acc[i][j][r]);
        }
      }
  }
  __syncthreads();

  if (EPI == 0) {
    ushort* C = (ushort*)Cout;
#pragma unroll
    for (int it = 0; it < 16; ++it) {
      int idx = it * 512 + t;
      int row = idx >> 5, ch = idx & 31;
      uint4 v = *(const uint4*)(lds + (row << 9) + ((ch << 4) ^ ((row & 7) << 4)));
      *(uint4*)(C + (size_t)(m0 + row) * N + n0 + (ch << 3)) = v;
    }
  } else if (EPI == 4) {
    ushort* C = (ushort*)Cout;
    if (n0 < 2048) {
#pragma unroll
      for (int it = 0; it < 16; ++it) {
        int idx = it * 512 + t;
        int row = idx >> 5, ch = idx & 31;
        uint4 v = *(const uint4*)(lds + (row << 9) + ((ch << 4) ^ ((row & 7) << 4)));
        *(uint4*)(C + (size_t)(m0 + row) * 2048 + n0 + (ch << 3)) = v;
      }
    } else {
      // V half -> tiled vtbuf. Fully linear store: elem = base + s*8.
      ushort* vC = C + (size_t)4096 * 2048;
      const int plane = (m0 >> 11) * NKVH + ((n0 - 2048) >> 8);
      ushort* dst = vC + (size_t)plane * ((size_t)NS * DH) + (size_t)((m0 & (NS - 1)) >> 5) * 8192;
#pragma unroll
      for (int it = 0; it < 16; ++it) {
        int s = it * 512 + t;
        int lr2 = s & 7, kq = (s >> 3) & 7, dt_l = (s >> 6) & 15, sb_l = s >> 10;
        int d0 = (dt_l << 4) + (lr2 << 1);   // lds col
        int r0 = (sb_l << 5) + (kq << 2);    // lds row (token)
        uint2 a = *(const uint2*)(lds + (d0 << 9) + ((r0 << 1) ^ ((d0 & 7) << 4)));
        uint2 b2 = *(const uint2*)(lds + ((d0 + 1) << 9) + ((r0 << 1) ^ (((d0 + 1) & 7) << 4)));
        uint4 v; v.x = a.x; v.y = a.y; v.z = b2.x; v.w = b2.y;
        *(uint4*)(dst + (size_t)s * 8) = v;
      }
    }
  } else {
    float* Cf = (float*)Cout;
#pragma unroll
    for (int it = 0; it < 32; ++it) {
      int idx = it * 512 + t;
      int row = idx >> 6, qd = idx & 63;
      ushort4 hv = *(const ushort4*)(lds + (row << 9) + ((qd << 3) ^ ((row & 7) << 4)));
      float4 fv;
      fv.x = bf2f(hv.x); fv.y = bf2f(hv.y); fv.z = bf2f(hv.z); fv.w = bf2f(hv.w);
      *(float4*)(Cf + (size_t)(m0 + row) * N + n0 + (qd << 2)) = fv;
    }
  }
}

// ---------------- RoPE in-place on bf16 [B*S][nheads*256], pairs (d,d+128) -
__global__ __launch_bounds__(256) void rope_kernel(ushort* __restrict__ buf,
                                                   const float* __restrict__ sint,
                                                   const float* __restrict__ cost,
                                                   int nheads) {
  int idx = (int)blockIdx.x * 256 + (int)threadIdx.x;
  int d = idx & 127;
  int h = (idx >> 7) % nheads;
  int tok = idx / (nheads << 7);
  int pos = tok & (NS - 1);
  float c = cost[pos * DH + d];
  float s = sint[pos * DH + d];
  size_t base = (size_t)tok * ((size_t)nheads * DH) + h * DH + d;
  float x1 = bf2f(buf[base]);
  float x2 = bf2f(buf[base + 128]);
  buf[base] = f2bf(x1 * c - x2 * s);
  buf[base + 128] = f2bf(x2 * c + x1 * s);
}

// ---------------- flash attention v4: QBLK=128, 8 waves, dbuf gload16 ------
// grid: B*NH*(S/128) = 512; block 512 = 8 waves, each wave 16 q-rows.
// 64KB LDS dbuf -> 2 blocks/CU = 16 waves/CU. Staging/barriers amortized over
// 2x MFMA vs QBLK=64. V in attn-tiled global layout -> fully linear gload16,
// bank-bijective PV reads. K: GEMM-proven chunk XOR (row&7). Fixed-max softmax.
__global__ __launch_bounds__(512) void attn_kernel(const ushort* __restrict__ q,
                                                   const ushort* __restrict__ k,
                                                   const ushort* __restrict__ vt,
                                                   ushort* __restrict__ ao) {
  __shared__ alignas(16) char lK[2][16384];
  __shared__ alignas(16) char lV[2][16384];
  const int bid = (int)blockIdx.x;
  const int qb = bid & 15;
  const int h = (bid >> 4) & 15;
  const int b = bid >> 8;
  const int kvh = h >> 1;
  const int qb0 = qb << 7;
  const int t = threadIdx.x;
  const int lane = t & 63;
  const int w = t >> 6;
  const int g = lane >> 4;
  const int lr = lane & 15;

  const int qrow = qb0 + (w << 4) + lr;
  bf16x8_t qf[8];
  const ushort* qbase = q + (size_t)(b * NS + qrow) * (NHEADS * DH) + h * DH;
#pragma unroll
  for (int ks = 0; ks < 8; ++ks)
    qf[ks] = *(const bf16x8_t*)(qbase + (ks << 5) + (g << 3));

  float l_r = 0.f;
  f32x4_t oacc[16] = {};

  const int qminw = qb0 + (w << 4);
  const int qmaxw = qminw + 15;
  int t_lo = qb0 - (WIN - 1);
  if (t_lo < 0) t_lo = 0;
  t_lo &= ~31;
  const int t_hi = qb0 + 127;
  const int nt = ((t_hi - t_lo) >> 5) + 1;

  const ushort* kgb = k + (size_t)(b * NS) * (NKVH * DH) + kvh * DH;
  const ushort* vgb = vt + (size_t)(b * NKVH + kvh) * ((size_t)NS * DH);

  auto stage = [&](int kt, int bi) {
    char* dk = lK[bi];
    char* dv = lV[bi];
    const int sb = kt >> 5;
#pragma unroll
    for (int j = 0; j < 2; ++j) {
      int i = (w << 1) + j;
      // K: issue i stages rows 2i, 2i+1 (1KB); source chunk pre-swizzled.
      int row = (i << 1) + (lane >> 5);
      int ck = (lane & 31) ^ (row & 7);
      gload16(kgb + (size_t)(kt + row) * (NKVH * DH) + (ck << 3), dk + (i << 10));
      // V: tiled layout, fully linear (16KB contiguous per 32-key tile).
      gload16(vgb + (size_t)sb * 8192 + (((i << 6) + lane) << 3), dv + (i << 10));
    }
  };

  int cur = 0;
  stage(t_lo, 0);
  __syncthreads();

  for (int i = 0; i < nt; ++i) {
    const int kt = t_lo + (i << 5);
    if (i + 1 < nt) stage(kt + 32, cur ^ 1);  // async prefetch into other buf
    const char* lk = lK[cur];
    const char* lv = lV[cur];
#pragma unroll
    for (int sub = 0; sub < 2; ++sub) {
      const int key0 = kt + (sub << 4);
      if (key0 > qmaxw) continue;
      if (key0 + 15 < qminw - (WIN - 1)) continue;

      f32x4_t sacc = {};
      __builtin_amdgcn_s_setprio(1);
#pragma unroll
      for (int ks = 0; ks < 8; ++ks) {
        int row = (sub << 4) + lr;
        bf16x8_t kf = *(const bf16x8_t*)(lk + (((row << 9) + (ks << 6) + (g << 4)) ^ ((row & 7) << 4)));
        sacc = __builtin_amdgcn_mfma_f32_16x16x32_bf16(kf, qf[ks], sacc, 0, 0, 0);
      }
      __builtin_amdgcn_s_setprio(0);

      float pvv[4];
      const bool full = (key0 + 15 <= qminw) && (key0 >= qmaxw - (WIN - 1));
      if (full) {
#pragma unroll
        for (int r = 0; r < 4; ++r) { pvv[r] = pexp(sacc[r]); l_r += pvv[r]; }
      } else {
#pragma unroll
        for (int r = 0; r < 4; ++r) {
          int key = key0 + (g << 2) + r;
          bool ok = (key <= qrow) && (qrow - key < WIN);
          pvv[r] = ok ? pexp(sacc[r]) : 0.f;
          l_r += pvv[r];
        }
      }

      s16x4_t pa;
      pa[0] = (short)f2bf(pvv[0]);
      pa[1] = (short)f2bf(pvv[1]);
      pa[2] = (short)f2bf(pvv[2]);
      pa[3] = (short)f2bf(pvv[3]);

      const int kqoff = ((sub << 2) + g) << 7;  // kq*128 bytes
      __builtin_amdgcn_s_setprio(1);
#pragma unroll
      for (int dt = 0; dt < 16; ++dt) {
        s16x4_t vf = *(const s16x4_t*)(lv + (dt << 10) + kqoff + (lr << 3));
        oacc[dt] = mfma_pv(pa, vf, oacc[dt]);
      }
      __builtin_amdgcn_s_setprio(0);
    }
    __syncthreads();  // drains gloads (next tile ready) + all waves done with cur
    cur ^= 1;
  }

  l_r += __shfl_xor(l_r, 16);
  l_r += __shfl_xor(l_r, 32);
  float dn[4];
#pragma unroll
  for (int r = 0; r < 4; ++r)
    dn[r] = 1.0f / __shfl(l_r, (g << 2) + r);

  const int orow0 = b * NS + qb0 + (w << 4) + (g << 2);
#pragma unroll
  for (int dt = 0; dt < 16; ++dt) {
    int col = h * DH + (dt << 4) + lr;
#pragma unroll
    for (int r = 0; r < 4; ++r) {
      ao[(size_t)(orow0 + r) * (NHEADS * DH) + col] = f2bf(oacc[dt][r] * dn[r]);
    }
  }
}

extern "C" void kernel_launch(void* const* d_in, const int* in_sizes, int n_in,
                              void* d_out, int out_size, void* d_ws, size_t ws_size,
                              hipStream_t stream) {
  const float* hs   = (const float*)d_in[0];
  const float* sint = (const float*)d_in[3];
  const float* cost = (const float*)d_in[4];
  const float* Wq = (const float*)d_in[6];
  const float* Wk = (const float*)d_in[7];
  const float* Wv = (const float*)d_in[8];
  const float* Wo = (const float*)d_in[9];

  char* ws = (char*)d_ws;
  size_t off = 0;
  auto alloc = [&](size_t bytes) {
    char* p = ws + off;
    off += (bytes + 255) & ~(size_t)255;
    return p;
  };
  ushort* hsb   = (ushort*)alloc((size_t)4096 * 3584 * 2);  // hs in bf16
  ushort* wT    = (ushort*)alloc((size_t)4096 * 3584 * 2);  // reused weight^T buffer
  ushort* qbuf  = (ushort*)alloc((size_t)4096 * 4096 * 2);
  ushort* kbuf  = (ushort*)alloc((size_t)4096 * 2048 * 2);  // MUST precede vtbuf
  ushort* vtbuf = (ushort*)alloc((size_t)4096 * 2048 * 2);  // = kbuf + 4096*2048 (tiled)
  ushort* aobuf = qbuf;  // alias: attn writes exactly the region only it reads
  if (off > ws_size) return;

  // hs f32 -> bf16
  f32_to_bf16_kernel<<<(4096 * 3584 / 4) / 256, 256, 0, stream>>>(hs, hsb, 4096 * 3584 / 4);

  // fused K+V projection: Bt = [WkT; WvT] stacked in wT
  transpose_f32_bf16<<<(3584 / 64) * (2048 / 64), 256, 0, stream>>>(Wk, wT, 3584, 2048);
  transpose_f32_bf16<<<(3584 / 64) * (2048 / 64), 256, 0, stream>>>(Wv, wT + (size_t)2048 * 3584, 3584, 2048);
  gemm256<4><<<16 * 16, 512, 0, stream>>>(hsb, wT, kbuf, 4096, 4096, 3584);

  // Q projection
  transpose_f32_bf16<<<(3584 / 64) * (4096 / 64), 256, 0, stream>>>(Wq, wT, 3584, 4096);
  gemm256<0><<<16 * 16, 512, 0, stream>>>(hsb, wT, qbuf, 4096, 4096, 3584);

  // RoPE (q then k), in-place
  rope_kernel<<<(4096 * 16 * 128) / 256, 256, 0, stream>>>(qbuf, sint, cost, 16);
  rope_kernel<<<(4096 * 8 * 128) / 256, 256, 0, stream>>>(kbuf, sint, cost, 8);

  // attention: QBLK=128, 8 waves (ao aliases qbuf)
  attn_kernel<<<NB * NHEADS * (NS / 128), 512, 0, stream>>>(qbuf, kbuf, vtbuf, aobuf);

  // output projection, f32 out
  transpose_f32_bf16<<<(4096 / 64) * (3584 / 64), 256, 0, stream>>>(Wo, wT, 4096, 3584);
  gemm256<2><<<16 * 14, 512, 0, stream>>>(aobuf, wT, d_out, 4096, 3584, 4096);
}